// Round 24
// baseline (93.800 us; speedup 1.0000x reference)
//
#include <hip/hip_runtime.h>
#include <hip/hip_bf16.h>

typedef unsigned int u32;
typedef unsigned long long u64;

#define HH 384
#define WW 768
#define HW (HH*WW)
#define H4 96
#define W4 192
#define DLR 32
#define TOPK 8000
#define NTH 256
#define NBLK (HW/NTH)    // 1152

// k_pn: conf region 66x6 (64x4 interior + 1px ring)
#define CNB 66
#define CNR 6
#define PTW 19
#define PTH 4

// jac tiling: interior 32x32, halo 16 -> region 64x64, 288 blocks, 512 thr
#define JIW 32
#define JIH 32
#define JH  16
#define JRW 64
#define JRH 64
#define JUPR (JRW/4)        // 16
#define JNU (JRH*JUPR)      // 1024
#define JNTH 512
#define JGX 24
#define JGRID 288

// k_sel: 16-bit bucket base (kept conf in [0.1,1) -> key>>16 in [0x3DCC,0x3F7F])
#define KB16 0x3DCCu
#define NB16 448

struct SelState { u32 K, cutoff, idxcut; };

// ---- compile-time D-interp tables (bit-identical weights to runtime formula) ----
struct DTab {
    float A[32]; float B[32];
    int f[32]; int l[32];
    float w[128];
};
constexpr DTab mk_dtab(){
    DTab t{};
    const float CD = (float)(31.0/127.0);
    for (int k = 0; k < 32; ++k){ t.A[k]=0.f; t.B[k]=0.f; t.f[k]=-1; t.l[k]=-1; }
    for (int d = 0; d < 128; ++d){
        float pos = (float)d * CD;
        int lo = (int)pos; if (lo > 31) lo = 31;
        int hi = (lo+1 > 31) ? 31 : lo+1;
        float w = pos - (float)lo;
        t.w[d] = w;
        t.A[lo] += 1.0f - w;            t.A[hi] += w;
        t.B[lo] += (float)d*(1.0f - w); t.B[hi] += (float)d*w;
        if (t.f[lo] < 0) t.f[lo] = d;
        t.l[lo] = d;
    }
    return t;
}
static constexpr DTab DT = mk_dtab();

// =============== k_pn: fused interp+conf (with 1px halo) + NMS + weights + list ===============
__global__ __launch_bounds__(NTH, 2) void k_pn(const float* __restrict__ P,
        const float* __restrict__ edge, const float* __restrict__ occ,
        float* __restrict__ conf, float* __restrict__ disp0, u32* __restrict__ dhk,
        float4* __restrict__ w4raw, u64* __restrict__ list, SelState* st){
    __shared__ float Sl[DLR][PTH][PTW];   // 9.5 KB
    __shared__ float YL[CNR][DLR][20];    // 15.4 KB
    __shared__ float Es[CNR][CNB];
    __shared__ float Os[CNR][CNB];
    __shared__ float Cs[CNR][CNB];
    __shared__ u32   Ds[CNR][CNB];

    int bx = blockIdx.x % 12, by = blockIdx.x / 12;
    int X = bx*64, Y = by*4;
    const float CY = (float)(95.0/383.0);
    const float CX = (float)(191.0/767.0);

    int yb = (Y > 0) ? (Y-1) : 0;
    int xb = (X > 0) ? (X-1) : 0;
    int y0min = (int)((float)yb * CY); if (y0min > H4-1) y0min = H4-1;
    int x0min = (int)((float)xb * CX); if (x0min > W4-1) x0min = W4-1;

    for (int e = threadIdx.x; e < DLR*PTH*PTW; e += NTH){
        int dl  = e / (PTH*PTW);
        int rem = e % (PTH*PTW);
        int ry  = rem / PTW;
        int cx  = rem % PTW;
        int gy = min(y0min + ry, H4-1);
        int gx = min(x0min + cx, W4-1);
        ((float*)Sl)[e] = P[dl*(H4*W4) + gy*W4 + gx];
    }
    for (int e = threadIdx.x; e < CNR*CNB; e += NTH){
        int ry = e / CNB, cx = e % CNB;
        int gy = min(max(Y + ry - 1, 0), HH-1);
        int gx = min(max(X + cx - 1, 0), WW-1);
        int cg = gy*WW + gx;
        Es[ry][cx] = edge[cg];
        Os[ry][cx] = occ[cg];
    }
    __syncthreads();

    for (int e = threadIdx.x; e < CNR*DLR*PTW; e += NTH){
        int row = e / (DLR*PTW);
        int rem = e % (DLR*PTW);
        int dl  = rem / PTW;
        int cx  = rem % PTW;
        int gyo = min(max(Y + row - 1, 0), HH-1);
        float fy = (float)gyo * CY;
        int y0 = (int)fy; if (y0 > H4-1) y0 = H4-1;
        int y1 = min(y0+1, H4-1);
        float wy = fy - (float)y0;
        int ry = y0 - y0min, ryb = y1 - y0min;
        YL[row][dl][cx] = Sl[dl][ry][cx]*(1.0f-wy) + Sl[dl][ryb][cx]*wy;
    }
    __syncthreads();

    // conf per region point; top-2/argmax via two independent even/odd chains
    // (bit-identical merge: candidate formulas unchanged; chain-extra runner
    // candidates are dominated; ties resolve to min segment index).
    auto conf_point = [&](int e){
        int ry = e / CNB, cx = e % CNB;
        int gy = Y + ry - 1, gx = X + cx - 1;
        bool in = ((u32)gy < (u32)HH) && ((u32)gx < (u32)WW);
        if (!in){ Cs[ry][cx] = -INFINITY; return; }

        float fx = (float)gx * CX;
        int x0 = (int)fx; if (x0 > W4-1) x0 = W4-1;
        float wx = fx - (float)x0;
        float omwx = 1.0f - wx;
        int cxl = x0 - x0min;

        float S[DLR];
        #pragma unroll
        for (int k = 0; k < DLR; ++k)
            S[k] = YL[ry][k][cxl]*omwx + YL[ry][k][cxl+1]*wx;

        float s0=0.f,s1=0.f,s2=0.f,s3=0.f, u0=0.f,u1=0.f,u2=0.f,u3=0.f;
        #pragma unroll
        for (int k = 0; k < DLR; k += 4){
            s0 = fmaf(DT.A[k  ], S[k  ], s0); u0 = fmaf(DT.B[k  ], S[k  ], u0);
            s1 = fmaf(DT.A[k+1], S[k+1], s1); u1 = fmaf(DT.B[k+1], S[k+1], u1);
            s2 = fmaf(DT.A[k+2], S[k+2], s2); u2 = fmaf(DT.B[k+2], S[k+2], u2);
            s3 = fmaf(DT.A[k+3], S[k+3], s3); u3 = fmaf(DT.B[k+3], S[k+3], u3);
        }
        float sum  = (s0+s1) + (s2+s3);
        float sumd = (u0+u1) + (u2+u3);

        float vmE = -1.f, v2E = -1.f; int dE = 0;
        float vmO = -1.f, v2O = -1.f; int dO = 0;
        #pragma unroll
        for (int k = 0; k < 32; ++k){
            if (DT.f[k] < 0) continue;
            const int d0 = DT.f[k], d1 = DT.l[k];
            const int kh = (k+1 > 31) ? 31 : k+1;
            float Sk = S[k], Sh = S[kh];
            const float w0 = DT.w[d0], w1 = DT.w[d1];
            float vf = Sk*(1.0f-w0) + Sh*w0;
            float vl = Sk*(1.0f-w1) + Sh*w1;
            bool up = vl > vf;
            float segv = up ? vl : vf;
            int   segd = up ? d1 : d0;
            float vr = -1.f;
            if (d1 > d0){
                const float wa = DT.w[d1-1], wb = DT.w[d0+1];
                float va = Sk*(1.0f-wa) + Sh*wa;
                float vb = Sk*(1.0f-wb) + Sh*wb;
                vr = up ? va : vb;
            }
            if ((k & 1) == 0){
                if (segv > vmE){ v2E = fmaxf(vmE, vr); vmE = segv; dE = segd; }
                else           { v2E = fmaxf(v2E, segv); }
            } else {
                if (segv > vmO){ v2O = fmaxf(vmO, vr); vmO = segv; dO = segd; }
                else           { v2O = fmaxf(v2O, segv); }
            }
        }
        float vmax; int dmax;
        if (vmE > vmO){ vmax = vmE; dmax = dE; }
        else if (vmO > vmE){ vmax = vmO; dmax = dO; }
        else { vmax = vmE; dmax = min(dE, dO); }
        float v2 = fmaxf(fmaxf(v2E, v2O), fminf(vmE, vmO));

        float inv  = 1.0f/(sum + 1e-6f);
        float pmax = vmax*inv, p2 = v2*inv;
        float psr  = pmax/(p2 + 1e-6f);
        float cf   = pmax * tanhf(psr);
        cf *= expf(-2.0f*Es[ry][cx]) * fmaxf(1.0f - Os[ry][cx], 0.0f);
        Cs[ry][cx] = cf;
        if (ry >= 1 && ry <= 4 && cx >= 1 && cx <= 64){
            int g = gy*WW + gx;
            conf[g]  = cf;
            disp0[g] = sumd*inv;
            Ds[ry][cx] = (u32)dmax;
        }
    };
    conf_point((int)threadIdx.x);
    if ((int)threadIdx.x + NTH < CNR*CNB) conf_point((int)threadIdx.x + NTH);
    __syncthreads();

    // NMS + edge weights + compact list append (block-aggregated single atomic)
    int lx = threadIdx.x & 63, ly = threadIdx.x >> 6;
    int x = X + lx, y = Y + ly;
    int idx = y*WW + x;

    float c = Cs[ly+1][lx+1];
    float pool = Cs[ly][lx];
    pool = fmaxf(pool, Cs[ly  ][lx+1]); pool = fmaxf(pool, Cs[ly  ][lx+2]);
    pool = fmaxf(pool, Cs[ly+1][lx  ]); pool = fmaxf(pool, Cs[ly+1][lx+1]);
    pool = fmaxf(pool, Cs[ly+1][lx+2]);
    pool = fmaxf(pool, Cs[ly+2][lx  ]); pool = fmaxf(pool, Cs[ly+2][lx+1]);
    pool = fmaxf(pool, Cs[ly+2][lx+2]);
    bool keep = (c >= 0.1f) && (c >= pool);
    dhk[idx] = Ds[ly+1][lx+1] | (keep ? 256u : 0u);

    float e  = Es[ly+1][lx+1], o  = Os[ly+1][lx+1];
    float e1 = Es[ly+2][lx+1], o1 = Os[ly+2][lx+1];
    float e2 = Es[ly  ][lx+1], o2 = Os[ly  ][lx+1];
    float e3 = Es[ly+1][lx+2], o3 = Os[ly+1][lx+2];
    float e4 = Es[ly+1][lx  ], o4 = Os[ly+1][lx  ];
    float4 wp;
    wp.x = expf(-(e+e1))*(1.f-o)*(1.f-o1);
    wp.y = expf(-(e+e2))*(1.f-o)*(1.f-o2);
    wp.z = expf(-(e+e3))*(1.f-o)*(1.f-o3);
    wp.w = expf(-(e+e4))*(1.f-o)*(1.f-o4);
    w4raw[idx] = wp;

    u64 m = __ballot(keep);
    int lane = threadIdx.x & 63, wid = threadIdx.x >> 6;
    __shared__ u32 wc[4];
    __shared__ u32 wpre[4];
    __shared__ u32 bb;
    if (lane == 0) wc[wid] = (u32)__popcll(m);
    __syncthreads();
    if (threadIdx.x == 0){
        u32 s = 0;
        #pragma unroll
        for (int w = 0; w < 4; ++w){ wpre[w] = s; s += wc[w]; }
        bb = atomicAdd(&st->K, s);
    }
    __syncthreads();
    if (keep){
        u32 before = (u32)__popcll(m & ((1ull << lane) - 1ull));
        list[bb + wpre[wid] + before] = ((u64)__float_as_uint(c) << 32) | (u32)idx;
    }
}

// =============== k_sel: single-block exact top-K cutoff (compact list) ===============
__global__ __launch_bounds__(1024) void k_sel(const u64* __restrict__ list,
        u64* __restrict__ side, SelState* st){
    u32 n = st->K;
    if (n <= TOPK){
        if (threadIdx.x == 0){ st->cutoff = 0; st->idxcut = 0x7FFFFFFFu; }
        return;
    }

    __shared__ u32 wh[16][NB16+1];   // per-wave histograms (padded)
    __shared__ u32 sc[512];
    __shared__ u32 hh[256];
    __shared__ u32 bc[3];
    __shared__ u32 snc;
    int t = threadIdx.x;
    int lane = t & 63, wv = t >> 6;

    // ---- Pass A: 448-bucket histogram over key>>16 ----
    for (int e = t; e < 16*(NB16+1); e += 1024) ((u32*)wh)[e] = 0;
    if (t == 0) snc = 0;
    __syncthreads();

    u32 nh = n >> 1;
    const ulonglong2* list2 = (const ulonglong2*)list;
    for (u32 p = t; p < nh; p += 1024){
        ulonglong2 e2 = list2[p];
        int b0 = (int)((u32)(e2.x >> 48)) - (int)KB16;
        int b1 = (int)((u32)(e2.y >> 48)) - (int)KB16;
        b0 = min(max(b0, 0), NB16-1);
        b1 = min(max(b1, 0), NB16-1);
        atomicAdd(&wh[wv][b0], 1u);
        atomicAdd(&wh[wv][b1], 1u);
    }
    if ((n & 1u) && t == 0){
        int b = (int)((u32)(list[n-1] >> 48)) - (int)KB16;
        b = min(max(b, 0), NB16-1);
        atomicAdd(&wh[0][b], 1u);
    }
    __syncthreads();

    // reduce 16 wave-hists -> sc[512] (descending layout), suffix-select
    u32 rem = TOPK;
    if (t < 512){
        u32 s = 0;
        int d = 511 - t;
        if (d < NB16){
            #pragma unroll
            for (int w = 0; w < 16; ++w) s += wh[w][d];
        }
        sc[t] = s;
    }
    __syncthreads();
    for (int off = 1; off < 512; off <<= 1){
        u32 add = (t < 512 && t >= off) ? sc[t - off] : 0;
        __syncthreads();
        if (t < 512) sc[t] += add;
        __syncthreads();
    }
    if (t < 512){
        u32 Sd  = sc[511 - t];
        u32 Sd1 = (t == 511) ? 0u : sc[511 - (t+1)];
        if (Sd >= rem && Sd1 < rem){ bc[0] = (u32)t; bc[1] = rem - Sd1; }
    }
    __syncthreads();
    u32 p16 = KB16 + bc[0];
    rem = bc[1];
    __syncthreads();

    // ---- Pass B: compact matching elements + byte1 histogram ----
    if (t < 256) hh[t] = 0;
    __syncthreads();
    u32 npad = (n + 1023u) & ~1023u;
    for (u32 i = t; i < npad; i += 1024){
        bool match = false; u64 e = 0; u32 key = 0;
        if (i < n){
            e = list[i];
            key = (u32)(e >> 32);
            match = (key >> 16) == p16;
        }
        u64 mb = __ballot(match);
        u32 cnt = (u32)__popcll(mb);
        if (cnt){
            int ldr = (int)(__ffsll((long long)mb) - 1);
            u32 base = 0;
            if (lane == ldr) base = atomicAdd(&snc, cnt);
            base = __shfl(base, ldr);
            if (match){
                u32 before = (u32)__popcll(mb & ((1ull << lane) - 1ull));
                side[base + before] = e;
                atomicAdd(&hh[(key >> 8) & 255u], 1u);
            }
        }
    }
    __syncthreads();
    u32 msz = snc;

    // byte1: descending suffix select over 256
    if (t < 256) sc[t] = hh[255 - t];
    __syncthreads();
    for (int off = 1; off < 256; off <<= 1){
        u32 add = (t < 256 && t >= off) ? sc[t - off] : 0;
        __syncthreads();
        if (t < 256) sc[t] += add;
        __syncthreads();
    }
    if (t < 256){
        u32 Sd  = sc[255 - t];
        u32 Sd1 = (t == 255) ? 0u : sc[255 - (t+1)];
        if (Sd >= rem && Sd1 < rem){ bc[0] = (u32)t; bc[1] = rem - Sd1; }
    }
    __syncthreads();
    u32 pref24 = (p16 << 8) | bc[0];
    rem = bc[1];
    __syncthreads();

    // byte0 over side buffer
    if (t < 256) hh[t] = 0;
    __syncthreads();
    u32 mpad = (msz + 1023u) & ~1023u;
    for (u32 i = t; i < mpad; i += 1024){
        if (i < msz){
            u32 key = (u32)(side[i] >> 32);
            if ((key >> 8) == pref24) atomicAdd(&hh[key & 255u], 1u);
        }
    }
    __syncthreads();
    if (t < 256) sc[t] = hh[255 - t];
    __syncthreads();
    for (int off = 1; off < 256; off <<= 1){
        u32 add = (t < 256 && t >= off) ? sc[t - off] : 0;
        __syncthreads();
        if (t < 256) sc[t] += add;
        __syncthreads();
    }
    if (t < 256){
        u32 Sd  = sc[255 - t];
        u32 Sd1 = (t == 255) ? 0u : sc[255 - (t+1)];
        if (Sd >= rem && Sd1 < rem){ bc[0] = (u32)t; bc[1] = rem - Sd1; bc[2] = hh[t]; }
    }
    __syncthreads();
    u32 cutoff = (pref24 << 8) | bc[0];
    rem = bc[1];
    u32 tie_h = bc[2];
    __syncthreads();

    // rare: rank ties by ascending pixel index over side buffer
    u32 idxcut = 0x7FFFFFFFu;
    if (rem != tie_h){
        u32 iprefix = 0, irem = rem;
        for (int b = 2; b >= 0; --b){
            if (t < 256) hh[t] = 0;
            __syncthreads();
            int shift = 8*b;
            for (u32 i = t; i < mpad; i += 1024){
                if (i < msz){
                    u64 e = side[i];
                    u32 key = (u32)(e >> 32);
                    u32 idx = (u32)e;
                    if (key == cutoff && (((u64)(idx ^ iprefix)) >> (shift+8)) == 0)
                        atomicAdd(&hh[(idx >> shift) & 255u], 1u);
                }
            }
            __syncthreads();
            if (t < 256) sc[t] = hh[t];
            __syncthreads();
            for (int off = 1; off < 256; off <<= 1){
                u32 add = (t < 256 && t >= off) ? sc[t - off] : 0;
                __syncthreads();
                if (t < 256) sc[t] += add;
                __syncthreads();
            }
            if (t < 256){
                u32 Pd = sc[t];
                u32 Pm = (t == 0) ? 0u : sc[t-1];
                if (Pd >= irem && Pm < irem){ bc[0] = (u32)t; bc[1] = irem - Pm; }
            }
            __syncthreads();
            iprefix |= bc[0] << shift; irem = bc[1];
            __syncthreads();
        }
        idxcut = iprefix;
    }
    if (t == 0){ st->cutoff = cutoff; st->idxcut = idxcut; }
}

// =============== jac: K sweeps; W/N/center in regs, R in LDS float4 units ===============
template<int FUSED, int FINAL>
__global__ __launch_bounds__(JNTH) void k_jacT(
        const float* __restrict__ Rin, float* __restrict__ Rout,
        const float4* __restrict__ Wp, const float* __restrict__ Nh,
        float4* __restrict__ Ws, float* __restrict__ Nho,
        const float* __restrict__ conf, const float* __restrict__ disp0,
        const u32* __restrict__ dhk, const SelState* __restrict__ st,
        float* __restrict__ out, int K){
    __shared__ float Rs[2][JRH*JRW];    // 2 x 16 KB
    int tid = threadIdx.x;
    int bx = blockIdx.x % JGX, by = blockIdx.x / JGX;
    int ry0 = by*JIH - JH, cx0 = bx*JIW - JH;

    float4 Wt[2][4];
    float4 Nt[2];
    float4 Ct[2];

    u32 cut = 0, idxcut = 0;
    if (FUSED){ cut = st->cutoff; idxcut = st->idxcut; }

    #pragma unroll
    for (int k = 0; k < 2; ++k){
        int u = tid + k*JNTH;
        int r = u / JUPR, c = (u % JUPR) << 2;
        int gy = ry0 + r;
        int cgy = min(max(gy,0),HH-1);
        float4 n4, r4;
        #pragma unroll
        for (int j = 0; j < 4; ++j){
            int gx = cx0 + c + j;
            int cgx = min(max(gx,0),WW-1);
            int g = cgy*WW + cgx;
            if (FUSED){
                u32 dv = dhk[g];
                float cf = conf[g];
                u32 key = __float_as_uint(cf);
                bool kf = (dv & 256u) &&
                          (key > cut || (key == cut && (u32)g <= idxcut));
                float mm = kf ? fminf(fmaxf(cf, 0.0f), 1.0f) : 0.0f;
                float4 wr = Wp[g];
                float wsum = wr.x + wr.y + wr.z + wr.w + 1e-6f;
                float den = mm + 0.8f*wsum + 1e-6f;
                float n0 = mm * ((float)(dv & 255u) - disp0[g]);
                float nh = n0 / den;
                float sc = 0.8f / den;
                wr.x *= sc; wr.y *= sc; wr.z *= sc; wr.w *= sc;
                Wt[k][j] = wr;
                ((float*)&n4)[j] = nh;
                ((float*)&r4)[j] = nh;
            } else {
                Wt[k][j] = Wp[g];
                ((float*)&n4)[j] = Nh[g];
                ((float*)&r4)[j] = Rin[g];
            }
        }
        Nt[k] = n4; Ct[k] = r4;
        *(float4*)&Rs[0][r*JRW + c] = r4;
        if (FUSED){
            if (r >= JH && r < JH+JIH && c >= JH && c < JH+JIW){
                int g2 = (ry0 + r)*WW + (cx0 + c);
                #pragma unroll
                for (int j = 0; j < 4; ++j) Ws[g2 + j] = Wt[k][j];
                *(float4*)&Nho[g2] = n4;
            }
        }
    }
    __syncthreads();

    int cur = 0;
    for (int ts = 1; ts <= K; ++ts){
        #pragma unroll
        for (int k = 0; k < 2; ++k){
            int u = tid + k*JNTH;
            int r = u / JUPR, c = (u % JUPR) << 2;
            int gy = ry0 + r;
            float4 C = Ct[k];
            int rm = (r > 0) ? r-1 : r;
            int rp = (r < JRH-1) ? r+1 : r;
            float4 up = *(const float4*)&Rs[cur][rm*JRW + c];
            float4 dn = *(const float4*)&Rs[cur][rp*JRW + c];
            if (gy == 0)    up = C;
            if (gy == HH-1) dn = C;
            float xl = Rs[cur][r*JRW + ((c > 0) ? c-1 : c)];
            float xr = Rs[cur][r*JRW + ((c+4 < JRW) ? c+4 : JRW-1)];
            int gx0 = cx0 + c;
            if (gx0 == 0)        xl = C.x;
            if (gx0 + 3 == WW-1) xr = C.w;
            float4 nv;
            nv.x = Nt[k].x + Wt[k][0].x*up.x + Wt[k][0].y*dn.x + Wt[k][0].z*xl  + Wt[k][0].w*C.y;
            nv.y = Nt[k].y + Wt[k][1].x*up.y + Wt[k][1].y*dn.y + Wt[k][1].z*C.x + Wt[k][1].w*C.z;
            nv.z = Nt[k].z + Wt[k][2].x*up.z + Wt[k][2].y*dn.z + Wt[k][2].z*C.y + Wt[k][2].w*C.w;
            nv.w = Nt[k].w + Wt[k][3].x*up.w + Wt[k][3].y*dn.w + Wt[k][3].z*C.z + Wt[k][3].w*xr;
            bool rowin = (r >= ts) && (r < JRH - ts);
            int cl = ts, ch = JRW - ts;
            nv.x = (rowin && c   >= cl && c   < ch) ? nv.x : C.x;
            nv.y = (rowin && c+1 >= cl && c+1 < ch) ? nv.y : C.y;
            nv.z = (rowin && c+2 >= cl && c+2 < ch) ? nv.z : C.z;
            nv.w = (rowin && c+3 >= cl && c+3 < ch) ? nv.w : C.w;
            *(float4*)&Rs[cur^1][r*JRW + c] = nv;
            Ct[k] = nv;
        }
        __syncthreads();
        cur ^= 1;
    }

    #pragma unroll
    for (int k = 0; k < 2; ++k){
        int u = tid + k*JNTH;
        int r = u / JUPR, c = (u % JUPR) << 2;
        if (r >= JH && r < JH+JIH && c >= JH && c < JH+JIW){
            int g = (ry0 + r)*WW + (cx0 + c);
            if (FINAL){
                float4 d0 = *(const float4*)&disp0[g];
                float4 o;
                o.x = fmaxf(d0.x + Ct[k].x, 0.0f);
                o.y = fmaxf(d0.y + Ct[k].y, 0.0f);
                o.z = fmaxf(d0.z + Ct[k].z, 0.0f);
                o.w = fmaxf(d0.w + Ct[k].w, 0.0f);
                *(float4*)&out[g] = o;
            } else {
                *(float4*)&Rout[g] = Ct[k];
            }
        }
    }
}

extern "C" void kernel_launch(void* const* d_in, const int* in_sizes, int n_in,
                              void* d_out, int out_size, void* d_ws, size_t ws_size,
                              hipStream_t stream) {
    const float* P    = (const float*)d_in[0];
    const float* edge = (const float*)d_in[1];
    const float* occ  = (const float*)d_in[2];
    float* out = (float*)d_out;

    float*  conf   = (float*)d_ws;
    float*  disp0  = conf + HW;
    float*  nhat   = disp0 + HW;
    float*  Ra     = nhat + HW;
    u32*    dhk    = (u32*)(Ra + HW);
    float4* w4raw  = (float4*)(dhk + HW);     // offset 20*HW B, 16B aligned
    float4* w4s    = w4raw + HW;
    u64*    list   = (u64*)(w4s + HW);        // 16B aligned
    u64*    side   = list + HW;
    SelState* st   = (SelState*)(side + HW);

    hipMemsetAsync(st, 0, sizeof(SelState), stream);
    k_pn<<<dim3(NBLK), dim3(NTH), 0, stream>>>(P, edge, occ, conf, disp0, dhk,
                                               w4raw, list, st);
    k_sel<<<1, 1024, 0, stream>>>(list, side, st);

    dim3 jgrid(JGRID), jblock(JNTH);
    // fused finalmaps: iter 1 staged + sweeps 2..16
    k_jacT<1,0><<<jgrid, jblock, 0, stream>>>(nullptr, Ra, w4raw, nullptr, w4s, nhat,
                                              conf, disp0, dhk, st, out, 15);
    // sweeps 17..30 + clip
    k_jacT<0,1><<<jgrid, jblock, 0, stream>>>(Ra, nullptr, w4s, nhat, nullptr, nullptr,
                                              conf, disp0, dhk, st, out, 14);
}

// Round 25
// 88.472 us; speedup vs baseline: 1.0602x; 1.0602x over previous
//
#include <hip/hip_runtime.h>
#include <hip/hip_bf16.h>

typedef unsigned int u32;
typedef unsigned long long u64;

#define HH 384
#define WW 768
#define HW (HH*WW)
#define H4 96
#define W4 192
#define DLR 32
#define TOPK 8000
#define NTH 256
#define NBLK (HW/NTH)    // 1152

// k_pn: conf region 66x6 (64x4 interior + 1px ring)
#define CNB 66
#define CNR 6
#define PTW 19
#define PTH 4

// jac tiling: interior 32x32, halo 16 -> region 64x64, 288 blocks, 512 thr
#define JIW 32
#define JIH 32
#define JH  16
#define JRW 64
#define JRH 64
#define JUPR (JRW/4)        // 16
#define JNU (JRH*JUPR)      // 1024
#define JNTH 512
#define JGX 24
#define JGRID 288

// k_sel: 16-bit bucket base (kept conf in [0.1,1) -> key>>16 in [0x3DCC,0x3F7F])
#define KB16 0x3DCCu
#define NB16 448

struct SelState { u32 K, cutoff, idxcut; };

// ---- compile-time D-interp tables (bit-identical weights to runtime formula) ----
struct DTab {
    float A[32]; float B[32];
    int f[32]; int l[32];
    float w[128];
};
constexpr DTab mk_dtab(){
    DTab t{};
    const float CD = (float)(31.0/127.0);
    for (int k = 0; k < 32; ++k){ t.A[k]=0.f; t.B[k]=0.f; t.f[k]=-1; t.l[k]=-1; }
    for (int d = 0; d < 128; ++d){
        float pos = (float)d * CD;
        int lo = (int)pos; if (lo > 31) lo = 31;
        int hi = (lo+1 > 31) ? 31 : lo+1;
        float w = pos - (float)lo;
        t.w[d] = w;
        t.A[lo] += 1.0f - w;            t.A[hi] += w;
        t.B[lo] += (float)d*(1.0f - w); t.B[hi] += (float)d*w;
        if (t.f[lo] < 0) t.f[lo] = d;
        t.l[lo] = d;
    }
    return t;
}
static constexpr DTab DT = mk_dtab();

// =============== k_pn: fused interp+conf (with 1px halo) + NMS + weights + list ===============
__global__ __launch_bounds__(NTH, 2) void k_pn(const float* __restrict__ P,
        const float* __restrict__ edge, const float* __restrict__ occ,
        float* __restrict__ conf, float* __restrict__ disp0, u32* __restrict__ dhk,
        float4* __restrict__ w4raw, u64* __restrict__ list, SelState* st){
    __shared__ float Sl[DLR][PTH][PTW];   // 9.5 KB
    __shared__ float YL[CNR][DLR][20];    // 15.4 KB
    __shared__ float Es[CNR][CNB];
    __shared__ float Os[CNR][CNB];
    __shared__ float Cs[CNR][CNB];
    __shared__ u32   Ds[CNR][CNB];

    int bx = blockIdx.x % 12, by = blockIdx.x / 12;
    int X = bx*64, Y = by*4;
    const float CY = (float)(95.0/383.0);
    const float CX = (float)(191.0/767.0);

    int yb = (Y > 0) ? (Y-1) : 0;
    int xb = (X > 0) ? (X-1) : 0;
    int y0min = (int)((float)yb * CY); if (y0min > H4-1) y0min = H4-1;
    int x0min = (int)((float)xb * CX); if (x0min > W4-1) x0min = W4-1;

    for (int e = threadIdx.x; e < DLR*PTH*PTW; e += NTH){
        int dl  = e / (PTH*PTW);
        int rem = e % (PTH*PTW);
        int ry  = rem / PTW;
        int cx  = rem % PTW;
        int gy = min(y0min + ry, H4-1);
        int gx = min(x0min + cx, W4-1);
        ((float*)Sl)[e] = P[dl*(H4*W4) + gy*W4 + gx];
    }
    for (int e = threadIdx.x; e < CNR*CNB; e += NTH){
        int ry = e / CNB, cx = e % CNB;
        int gy = min(max(Y + ry - 1, 0), HH-1);
        int gx = min(max(X + cx - 1, 0), WW-1);
        int cg = gy*WW + gx;
        Es[ry][cx] = edge[cg];
        Os[ry][cx] = occ[cg];
    }
    __syncthreads();

    for (int e = threadIdx.x; e < CNR*DLR*PTW; e += NTH){
        int row = e / (DLR*PTW);
        int rem = e % (DLR*PTW);
        int dl  = rem / PTW;
        int cx  = rem % PTW;
        int gyo = min(max(Y + row - 1, 0), HH-1);
        float fy = (float)gyo * CY;
        int y0 = (int)fy; if (y0 > H4-1) y0 = H4-1;
        int y1 = min(y0+1, H4-1);
        float wy = fy - (float)y0;
        int ry = y0 - y0min, ryb = y1 - y0min;
        YL[row][dl][cx] = Sl[dl][ry][cx]*(1.0f-wy) + Sl[dl][ryb][cx]*wy;
    }
    __syncthreads();

    auto conf_point = [&](int e){
        int ry = e / CNB, cx = e % CNB;
        int gy = Y + ry - 1, gx = X + cx - 1;
        bool in = ((u32)gy < (u32)HH) && ((u32)gx < (u32)WW);
        if (!in){ Cs[ry][cx] = -INFINITY; return; }

        float fx = (float)gx * CX;
        int x0 = (int)fx; if (x0 > W4-1) x0 = W4-1;
        float wx = fx - (float)x0;
        float omwx = 1.0f - wx;
        int cxl = x0 - x0min;

        float S[DLR];
        #pragma unroll
        for (int k = 0; k < DLR; ++k){
            S[k] = YL[ry][k][cxl]*omwx + YL[ry][k][cxl+1]*wx;
            asm volatile("" : "+v"(S[k]));
        }

        float s0=0.f,s1=0.f,s2=0.f,s3=0.f, u0=0.f,u1=0.f,u2=0.f,u3=0.f;
        #pragma unroll
        for (int k = 0; k < DLR; k += 4){
            s0 = fmaf(DT.A[k  ], S[k  ], s0); u0 = fmaf(DT.B[k  ], S[k  ], u0);
            s1 = fmaf(DT.A[k+1], S[k+1], s1); u1 = fmaf(DT.B[k+1], S[k+1], u1);
            s2 = fmaf(DT.A[k+2], S[k+2], s2); u2 = fmaf(DT.B[k+2], S[k+2], u2);
            s3 = fmaf(DT.A[k+3], S[k+3], s3); u3 = fmaf(DT.B[k+3], S[k+3], u3);
        }
        float sum  = (s0+s1) + (s2+s3);
        float sumd = (u0+u1) + (u2+u3);

        float vmax = -1.f, v2 = -1.f; int dmax = 0;
        #pragma unroll
        for (int k = 0; k < 32; ++k){
            if (DT.f[k] < 0) continue;
            const int d0 = DT.f[k], d1 = DT.l[k];
            const int kh = (k+1 > 31) ? 31 : k+1;
            float Sk = S[k], Sh = S[kh];
            const float w0 = DT.w[d0], w1 = DT.w[d1];
            float vf = Sk*(1.0f-w0) + Sh*w0;
            float vl = Sk*(1.0f-w1) + Sh*w1;
            bool up = vl > vf;
            float segv = up ? vl : vf;
            int   segd = up ? d1 : d0;
            float vr = -1.f;
            if (d1 > d0){
                const float wa = DT.w[d1-1], wb = DT.w[d0+1];
                float va = Sk*(1.0f-wa) + Sh*wa;
                float vb = Sk*(1.0f-wb) + Sh*wb;
                vr = up ? va : vb;
            }
            if (segv > vmax){ v2 = fmaxf(vmax, vr); vmax = segv; dmax = segd; }
            else            { v2 = fmaxf(v2, segv); }
        }

        float inv  = 1.0f/(sum + 1e-6f);
        float pmax = vmax*inv, p2 = v2*inv;
        float psr  = pmax/(p2 + 1e-6f);
        float cf   = pmax * tanhf(psr);
        cf *= expf(-2.0f*Es[ry][cx]) * fmaxf(1.0f - Os[ry][cx], 0.0f);
        Cs[ry][cx] = cf;
        if (ry >= 1 && ry <= 4 && cx >= 1 && cx <= 64){
            int g = gy*WW + gx;
            conf[g]  = cf;
            disp0[g] = sumd*inv;
            Ds[ry][cx] = (u32)dmax;
        }
    };
    conf_point((int)threadIdx.x);
    if ((int)threadIdx.x + NTH < CNR*CNB) conf_point((int)threadIdx.x + NTH);
    __syncthreads();

    // NMS + edge weights + compact list append (block-aggregated single atomic)
    int lx = threadIdx.x & 63, ly = threadIdx.x >> 6;
    int x = X + lx, y = Y + ly;
    int idx = y*WW + x;

    float c = Cs[ly+1][lx+1];
    float pool = Cs[ly][lx];
    pool = fmaxf(pool, Cs[ly  ][lx+1]); pool = fmaxf(pool, Cs[ly  ][lx+2]);
    pool = fmaxf(pool, Cs[ly+1][lx  ]); pool = fmaxf(pool, Cs[ly+1][lx+1]);
    pool = fmaxf(pool, Cs[ly+1][lx+2]);
    pool = fmaxf(pool, Cs[ly+2][lx  ]); pool = fmaxf(pool, Cs[ly+2][lx+1]);
    pool = fmaxf(pool, Cs[ly+2][lx+2]);
    bool keep = (c >= 0.1f) && (c >= pool);
    dhk[idx] = Ds[ly+1][lx+1] | (keep ? 256u : 0u);

    float e  = Es[ly+1][lx+1], o  = Os[ly+1][lx+1];
    float e1 = Es[ly+2][lx+1], o1 = Os[ly+2][lx+1];
    float e2 = Es[ly  ][lx+1], o2 = Os[ly  ][lx+1];
    float e3 = Es[ly+1][lx+2], o3 = Os[ly+1][lx+2];
    float e4 = Es[ly+1][lx  ], o4 = Os[ly+1][lx  ];
    float4 wp;
    wp.x = expf(-(e+e1))*(1.f-o)*(1.f-o1);
    wp.y = expf(-(e+e2))*(1.f-o)*(1.f-o2);
    wp.z = expf(-(e+e3))*(1.f-o)*(1.f-o3);
    wp.w = expf(-(e+e4))*(1.f-o)*(1.f-o4);
    w4raw[idx] = wp;

    u64 m = __ballot(keep);
    int lane = threadIdx.x & 63, wid = threadIdx.x >> 6;
    __shared__ u32 wc[4];
    __shared__ u32 wpre[4];
    __shared__ u32 bb;
    if (lane == 0) wc[wid] = (u32)__popcll(m);
    __syncthreads();
    if (threadIdx.x == 0){
        u32 s = 0;
        #pragma unroll
        for (int w = 0; w < 4; ++w){ wpre[w] = s; s += wc[w]; }
        bb = atomicAdd(&st->K, s);
    }
    __syncthreads();
    if (keep){
        u32 before = (u32)__popcll(m & ((1ull << lane) - 1ull));
        list[bb + wpre[wid] + before] = ((u64)__float_as_uint(c) << 32) | (u32)idx;
    }
}

// =============== k_sel: single-block exact top-K cutoff (compact list) ===============
__global__ __launch_bounds__(1024) void k_sel(const u64* __restrict__ list,
        u64* __restrict__ side, SelState* st){
    u32 n = st->K;
    if (n <= TOPK){
        if (threadIdx.x == 0){ st->cutoff = 0; st->idxcut = 0x7FFFFFFFu; }
        return;
    }

    __shared__ u32 wh[16][NB16+1];   // per-wave histograms (padded)
    __shared__ u32 sc[512];
    __shared__ u32 hh[256];
    __shared__ u32 bc[3];
    __shared__ u32 snc;
    int t = threadIdx.x;
    int lane = t & 63, wv = t >> 6;

    // ---- Pass A: 448-bucket histogram over key>>16 ----
    for (int e = t; e < 16*(NB16+1); e += 1024) ((u32*)wh)[e] = 0;
    if (t == 0) snc = 0;
    __syncthreads();

    u32 nh = n >> 1;
    const ulonglong2* list2 = (const ulonglong2*)list;
    for (u32 p = t; p < nh; p += 1024){
        ulonglong2 e2 = list2[p];
        int b0 = (int)((u32)(e2.x >> 48)) - (int)KB16;
        int b1 = (int)((u32)(e2.y >> 48)) - (int)KB16;
        b0 = min(max(b0, 0), NB16-1);
        b1 = min(max(b1, 0), NB16-1);
        atomicAdd(&wh[wv][b0], 1u);
        atomicAdd(&wh[wv][b1], 1u);
    }
    if ((n & 1u) && t == 0){
        int b = (int)((u32)(list[n-1] >> 48)) - (int)KB16;
        b = min(max(b, 0), NB16-1);
        atomicAdd(&wh[0][b], 1u);
    }
    __syncthreads();

    // reduce 16 wave-hists -> sc[512] (descending layout), suffix-select
    u32 rem = TOPK;
    if (t < 512){
        u32 s = 0;
        int d = 511 - t;
        if (d < NB16){
            #pragma unroll
            for (int w = 0; w < 16; ++w) s += wh[w][d];
        }
        sc[t] = s;
    }
    __syncthreads();
    for (int off = 1; off < 512; off <<= 1){
        u32 add = (t < 512 && t >= off) ? sc[t - off] : 0;
        __syncthreads();
        if (t < 512) sc[t] += add;
        __syncthreads();
    }
    if (t < 512){
        u32 Sd  = sc[511 - t];
        u32 Sd1 = (t == 511) ? 0u : sc[511 - (t+1)];
        if (Sd >= rem && Sd1 < rem){ bc[0] = (u32)t; bc[1] = rem - Sd1; }
    }
    __syncthreads();
    u32 p16 = KB16 + bc[0];
    rem = bc[1];
    __syncthreads();

    // ---- Pass B: compact matching elements + byte1 histogram ----
    if (t < 256) hh[t] = 0;
    __syncthreads();
    u32 npad = (n + 1023u) & ~1023u;
    for (u32 i = t; i < npad; i += 1024){
        bool match = false; u64 e = 0; u32 key = 0;
        if (i < n){
            e = list[i];
            key = (u32)(e >> 32);
            match = (key >> 16) == p16;
        }
        u64 mb = __ballot(match);
        u32 cnt = (u32)__popcll(mb);
        if (cnt){
            int ldr = (int)(__ffsll((long long)mb) - 1);
            u32 base = 0;
            if (lane == ldr) base = atomicAdd(&snc, cnt);
            base = __shfl(base, ldr);
            if (match){
                u32 before = (u32)__popcll(mb & ((1ull << lane) - 1ull));
                side[base + before] = e;
                atomicAdd(&hh[(key >> 8) & 255u], 1u);
            }
        }
    }
    __syncthreads();
    u32 msz = snc;

    // byte1: descending suffix select over 256
    if (t < 256) sc[t] = hh[255 - t];
    __syncthreads();
    for (int off = 1; off < 256; off <<= 1){
        u32 add = (t < 256 && t >= off) ? sc[t - off] : 0;
        __syncthreads();
        if (t < 256) sc[t] += add;
        __syncthreads();
    }
    if (t < 256){
        u32 Sd  = sc[255 - t];
        u32 Sd1 = (t == 255) ? 0u : sc[255 - (t+1)];
        if (Sd >= rem && Sd1 < rem){ bc[0] = (u32)t; bc[1] = rem - Sd1; }
    }
    __syncthreads();
    u32 pref24 = (p16 << 8) | bc[0];
    rem = bc[1];
    __syncthreads();

    // byte0 over side buffer
    if (t < 256) hh[t] = 0;
    __syncthreads();
    u32 mpad = (msz + 1023u) & ~1023u;
    for (u32 i = t; i < mpad; i += 1024){
        if (i < msz){
            u32 key = (u32)(side[i] >> 32);
            if ((key >> 8) == pref24) atomicAdd(&hh[key & 255u], 1u);
        }
    }
    __syncthreads();
    if (t < 256) sc[t] = hh[255 - t];
    __syncthreads();
    for (int off = 1; off < 256; off <<= 1){
        u32 add = (t < 256 && t >= off) ? sc[t - off] : 0;
        __syncthreads();
        if (t < 256) sc[t] += add;
        __syncthreads();
    }
    if (t < 256){
        u32 Sd  = sc[255 - t];
        u32 Sd1 = (t == 255) ? 0u : sc[255 - (t+1)];
        if (Sd >= rem && Sd1 < rem){ bc[0] = (u32)t; bc[1] = rem - Sd1; bc[2] = hh[t]; }
    }
    __syncthreads();
    u32 cutoff = (pref24 << 8) | bc[0];
    rem = bc[1];
    u32 tie_h = bc[2];
    __syncthreads();

    // rare: rank ties by ascending pixel index over side buffer
    u32 idxcut = 0x7FFFFFFFu;
    if (rem != tie_h){
        u32 iprefix = 0, irem = rem;
        for (int b = 2; b >= 0; --b){
            if (t < 256) hh[t] = 0;
            __syncthreads();
            int shift = 8*b;
            for (u32 i = t; i < mpad; i += 1024){
                if (i < msz){
                    u64 e = side[i];
                    u32 key = (u32)(e >> 32);
                    u32 idx = (u32)e;
                    if (key == cutoff && (((u64)(idx ^ iprefix)) >> (shift+8)) == 0)
                        atomicAdd(&hh[(idx >> shift) & 255u], 1u);
                }
            }
            __syncthreads();
            if (t < 256) sc[t] = hh[t];
            __syncthreads();
            for (int off = 1; off < 256; off <<= 1){
                u32 add = (t < 256 && t >= off) ? sc[t - off] : 0;
                __syncthreads();
                if (t < 256) sc[t] += add;
                __syncthreads();
            }
            if (t < 256){
                u32 Pd = sc[t];
                u32 Pm = (t == 0) ? 0u : sc[t-1];
                if (Pd >= irem && Pm < irem){ bc[0] = (u32)t; bc[1] = irem - Pm; }
            }
            __syncthreads();
            iprefix |= bc[0] << shift; irem = bc[1];
            __syncthreads();
        }
        idxcut = iprefix;
    }
    if (t == 0){ st->cutoff = cutoff; st->idxcut = idxcut; }
}

// =============== jac: K sweeps; W/N/center in regs, R in LDS float4 units ===============
template<int FUSED, int FINAL>
__global__ __launch_bounds__(JNTH) void k_jacT(
        const float* __restrict__ Rin, float* __restrict__ Rout,
        const float4* __restrict__ Wp, const float* __restrict__ Nh,
        float4* __restrict__ Ws, float* __restrict__ Nho,
        const float* __restrict__ conf, const float* __restrict__ disp0,
        const u32* __restrict__ dhk, const SelState* __restrict__ st,
        float* __restrict__ out, int K){
    __shared__ float Rs[2][JRH*JRW];    // 2 x 16 KB
    int tid = threadIdx.x;
    int bx = blockIdx.x % JGX, by = blockIdx.x / JGX;
    int ry0 = by*JIH - JH, cx0 = bx*JIW - JH;

    float4 Wt[2][4];
    float4 Nt[2];
    float4 Ct[2];

    u32 cut = 0, idxcut = 0;
    if (FUSED){ cut = st->cutoff; idxcut = st->idxcut; }

    #pragma unroll
    for (int k = 0; k < 2; ++k){
        int u = tid + k*JNTH;
        int r = u / JUPR, c = (u % JUPR) << 2;
        int gy = ry0 + r;
        int cgy = min(max(gy,0),HH-1);
        float4 n4, r4;
        #pragma unroll
        for (int j = 0; j < 4; ++j){
            int gx = cx0 + c + j;
            int cgx = min(max(gx,0),WW-1);
            int g = cgy*WW + cgx;
            if (FUSED){
                u32 dv = dhk[g];
                float cf = conf[g];
                u32 key = __float_as_uint(cf);
                bool kf = (dv & 256u) &&
                          (key > cut || (key == cut && (u32)g <= idxcut));
                float mm = kf ? fminf(fmaxf(cf, 0.0f), 1.0f) : 0.0f;
                float4 wr = Wp[g];
                float wsum = wr.x + wr.y + wr.z + wr.w + 1e-6f;
                float den = mm + 0.8f*wsum + 1e-6f;
                float n0 = mm * ((float)(dv & 255u) - disp0[g]);
                float nh = n0 / den;
                float sc = 0.8f / den;
                wr.x *= sc; wr.y *= sc; wr.z *= sc; wr.w *= sc;
                Wt[k][j] = wr;
                ((float*)&n4)[j] = nh;
                ((float*)&r4)[j] = nh;
            } else {
                Wt[k][j] = Wp[g];
                ((float*)&n4)[j] = Nh[g];
                ((float*)&r4)[j] = Rin[g];
            }
        }
        Nt[k] = n4; Ct[k] = r4;
        *(float4*)&Rs[0][r*JRW + c] = r4;
        if (FUSED){
            if (r >= JH && r < JH+JIH && c >= JH && c < JH+JIW){
                int g2 = (ry0 + r)*WW + (cx0 + c);
                #pragma unroll
                for (int j = 0; j < 4; ++j) Ws[g2 + j] = Wt[k][j];
                *(float4*)&Nho[g2] = n4;
            }
        }
    }
    __syncthreads();

    int cur = 0;
    for (int ts = 1; ts <= K; ++ts){
        #pragma unroll
        for (int k = 0; k < 2; ++k){
            int u = tid + k*JNTH;
            int r = u / JUPR, c = (u % JUPR) << 2;
            int gy = ry0 + r;
            float4 C = Ct[k];
            int rm = (r > 0) ? r-1 : r;
            int rp = (r < JRH-1) ? r+1 : r;
            float4 up = *(const float4*)&Rs[cur][rm*JRW + c];
            float4 dn = *(const float4*)&Rs[cur][rp*JRW + c];
            if (gy == 0)    up = C;
            if (gy == HH-1) dn = C;
            float xl = Rs[cur][r*JRW + ((c > 0) ? c-1 : c)];
            float xr = Rs[cur][r*JRW + ((c+4 < JRW) ? c+4 : JRW-1)];
            int gx0 = cx0 + c;
            if (gx0 == 0)        xl = C.x;
            if (gx0 + 3 == WW-1) xr = C.w;
            float4 nv;
            nv.x = Nt[k].x + Wt[k][0].x*up.x + Wt[k][0].y*dn.x + Wt[k][0].z*xl  + Wt[k][0].w*C.y;
            nv.y = Nt[k].y + Wt[k][1].x*up.y + Wt[k][1].y*dn.y + Wt[k][1].z*C.x + Wt[k][1].w*C.z;
            nv.z = Nt[k].z + Wt[k][2].x*up.z + Wt[k][2].y*dn.z + Wt[k][2].z*C.y + Wt[k][2].w*C.w;
            nv.w = Nt[k].w + Wt[k][3].x*up.w + Wt[k][3].y*dn.w + Wt[k][3].z*C.z + Wt[k][3].w*xr;
            bool rowin = (r >= ts) && (r < JRH - ts);
            int cl = ts, ch = JRW - ts;
            nv.x = (rowin && c   >= cl && c   < ch) ? nv.x : C.x;
            nv.y = (rowin && c+1 >= cl && c+1 < ch) ? nv.y : C.y;
            nv.z = (rowin && c+2 >= cl && c+2 < ch) ? nv.z : C.z;
            nv.w = (rowin && c+3 >= cl && c+3 < ch) ? nv.w : C.w;
            *(float4*)&Rs[cur^1][r*JRW + c] = nv;
            Ct[k] = nv;
        }
        __syncthreads();
        cur ^= 1;
    }

    #pragma unroll
    for (int k = 0; k < 2; ++k){
        int u = tid + k*JNTH;
        int r = u / JUPR, c = (u % JUPR) << 2;
        if (r >= JH && r < JH+JIH && c >= JH && c < JH+JIW){
            int g = (ry0 + r)*WW + (cx0 + c);
            if (FINAL){
                float4 d0 = *(const float4*)&disp0[g];
                float4 o;
                o.x = fmaxf(d0.x + Ct[k].x, 0.0f);
                o.y = fmaxf(d0.y + Ct[k].y, 0.0f);
                o.z = fmaxf(d0.z + Ct[k].z, 0.0f);
                o.w = fmaxf(d0.w + Ct[k].w, 0.0f);
                *(float4*)&out[g] = o;
            } else {
                *(float4*)&Rout[g] = Ct[k];
            }
        }
    }
}

extern "C" void kernel_launch(void* const* d_in, const int* in_sizes, int n_in,
                              void* d_out, int out_size, void* d_ws, size_t ws_size,
                              hipStream_t stream) {
    const float* P    = (const float*)d_in[0];
    const float* edge = (const float*)d_in[1];
    const float* occ  = (const float*)d_in[2];
    float* out = (float*)d_out;

    float*  conf   = (float*)d_ws;
    float*  disp0  = conf + HW;
    float*  nhat   = disp0 + HW;
    float*  Ra     = nhat + HW;
    u32*    dhk    = (u32*)(Ra + HW);
    float4* w4raw  = (float4*)(dhk + HW);     // offset 20*HW B, 16B aligned
    float4* w4s    = w4raw + HW;
    u64*    list   = (u64*)(w4s + HW);        // 16B aligned
    u64*    side   = list + HW;
    SelState* st   = (SelState*)(side + HW);

    hipMemsetAsync(st, 0, sizeof(SelState), stream);
    k_pn<<<dim3(NBLK), dim3(NTH), 0, stream>>>(P, edge, occ, conf, disp0, dhk,
                                               w4raw, list, st);
    k_sel<<<1, 1024, 0, stream>>>(list, side, st);

    dim3 jgrid(JGRID), jblock(JNTH);
    // fused finalmaps: iter 1 staged + sweeps 2..16
    k_jacT<1,0><<<jgrid, jblock, 0, stream>>>(nullptr, Ra, w4raw, nullptr, w4s, nhat,
                                              conf, disp0, dhk, st, out, 15);
    // sweeps 17..30 + clip
    k_jacT<0,1><<<jgrid, jblock, 0, stream>>>(Ra, nullptr, w4s, nhat, nullptr, nullptr,
                                              conf, disp0, dhk, st, out, 14);
}